// Round 10
// baseline (307.432 us; speedup 1.0000x reference)
//
#include <hip/hip_runtime.h>
#include <hip/hip_bf16.h>

// Problem constants (reference: B=2, N=20000, K=16, DIM=256)
// Established facts (R1-R9):
//   - float tensors fp32; idx int32/int64 runtime-detected; d_out fp32
//   - MFMA 16x16x32_bf16 gemm-BT fragments + C/D map verified
//   - R5-R8: global->VGPR weight loads emit load->vmcnt(0)->use chains; dead end
//   - R9: per-kk DMA+barrier structure = ~1800 cyc/iter (latency-serialized,
//     3 co-resident blocks don't cover the drain). This round: weight-
//     stationary 64 KB LDS halves, ONE barrier per block, barrier-free M-loop.
#define BN   40000
#define NPTS 20000
#define KNN  16
#define DIM  256

typedef __attribute__((ext_vector_type(8))) short bf16x8;   // 8 bf16 = 4 VGPRs
typedef __attribute__((ext_vector_type(4))) float f32x4;

__device__ __forceinline__ float lrelu(float v) { return v > 0.f ? v : 0.1f * v; }
__device__ __forceinline__ float bs2f(short s) {
    union { unsigned u; float f; } c; c.u = ((unsigned)(unsigned short)s) << 16;
    return c.f;
}
__device__ __forceinline__ short f2bs(float f) {
    __hip_bfloat16 h = __float2bfloat16(f);           // RNE
    return *reinterpret_cast<short*>(&h);
}
__device__ __forceinline__ bf16x8 ldf32_bf16x8(const float* p) {
    const float4 a = ((const float4*)p)[0];
    const float4 b = ((const float4*)p)[1];
    bf16x8 r;
    r[0]=f2bs(a.x); r[1]=f2bs(a.y); r[2]=f2bs(a.z); r[3]=f2bs(a.w);
    r[4]=f2bs(b.x); r[5]=f2bs(b.y); r[6]=f2bs(b.z); r[7]=f2bs(b.w);
    return r;
}

// async global->LDS, 16 B per lane; lds dst = wave-uniform base + lane*16.
__device__ __forceinline__ void dma16(const void* g, void* l) {
    __builtin_amdgcn_global_load_lds(
        (const __attribute__((address_space(1))) unsigned int*)g,
        (__attribute__((address_space(3))) unsigned int*)l, 16, 0, 0);
}

// ---------------------------------------------------------------------------
// geom MLPs (blocks 0..3749) + idx-dtype detect (block 3750) + weight
// conversion (blocks 3751..3894).
// conv: Wf,Wi -> per-matrix kk-tiled bf16 Wt[kk][q][n][8] (128 KB each;
//       64 KB n-half is DMA-contiguous per (kk,q)); W_init -> linear Wnb.
// ---------------------------------------------------------------------------
__global__ void __launch_bounds__(256) geom_kernel(
    const float* __restrict__ geom,      // [BN,16,4]
    const float* __restrict__ W1, const float* __restrict__ B1,   // [64,4],[64]
    const float* __restrict__ W2, const float* __restrict__ B2,   // [128,4],[128]
    const int* __restrict__ idxw, int* __restrict__ flag,
    const float* __restrict__ Wf, const float* __restrict__ Wi,   // [256,256]
    const float* __restrict__ Wn,                                  // [64,256]
    short* __restrict__ WtF, short* __restrict__ WtI, short* __restrict__ Wnb,
    __hip_bfloat16* __restrict__ x2,     // [BN,128]
    __hip_bfloat16* __restrict__ x3)     // [BN,256]
{
    if (blockIdx.x >= 3751) {            // ---- weight-convert blocks ----
        int t = (blockIdx.x - 3751) * 256 + threadIdx.x;   // < 36864 exactly
        if (t < 32768) {                 // Wf (t<16384) / Wi -> tiled
            int mat = t >> 14;
            int tt  = t & 16383;
            float4 v = mat ? ((const float4*)Wi)[tt] : ((const float4*)Wf)[tt];
            int n  = tt >> 6;
            int k  = (tt & 63) * 4;
            int kk = k >> 5, q = (k >> 3) & 3, j = k & 7;
            short4 o; o.x=f2bs(v.x); o.y=f2bs(v.y); o.z=f2bs(v.z); o.w=f2bs(v.w);
            short* dst = mat ? WtI : WtF;
            *(short4*)(dst + ((size_t)((kk*4 + q)*256 + n))*8 + j) = o;
        } else {                          // W_init -> linear Wnb
            int tt = t - 32768;           // < 4096
            float4 v = ((const float4*)Wn)[tt];
            short4 o; o.x=f2bs(v.x); o.y=f2bs(v.y); o.z=f2bs(v.z); o.w=f2bs(v.w);
            ((short4*)Wnb)[tt] = o;
        }
        return;
    }
    if (blockIdx.x == 3750) {            // ---- detect block (no atomics) ----
        __shared__ int red[256];
        int t = threadIdx.x;
        int v = 0;
#pragma unroll
        for (int it = 0; it < 64; ++it)
            v |= idxw[2 * (t + it * 256) + 1];       // odd words, first 128 KB
        red[t] = v;
        __syncthreads();
        for (int s = 128; s > 0; s >>= 1) {
            if (t < s) red[t] |= red[t + s];
            __syncthreads();
        }
        if (t == 0) *flag = (red[0] != 0) ? 1 : 0;
        return;
    }
    // ---- geom blocks: 3750 x 256 = 960000 threads = 40000 pts x 24 ----
    int tid = blockIdx.x * 256 + threadIdx.x;
    int p  = tid / 24;
    int cg = tid - p * 24;               // 0..23 -> 8 channels each
    const float4* g = (const float4*)(geom + (size_t)p * (KNN * 4));
    const float4* Wp; const float* Bp; int c0;
    if (cg < 8) { c0 = cg * 8;       Wp = (const float4*)W1; Bp = B1; }
    else        { c0 = (cg - 8) * 8; Wp = (const float4*)W2; Bp = B2; }
    float4 w[8]; float bb[8];
#pragma unroll
    for (int j = 0; j < 8; ++j) { w[j] = Wp[c0 + j]; bb[j] = Bp[c0 + j]; }
    float acc[8];
#pragma unroll
    for (int j = 0; j < 8; ++j) acc[j] = 0.f;
#pragma unroll
    for (int k = 0; k < KNN; ++k) {
        float4 gv = g[k];
#pragma unroll
        for (int j = 0; j < 8; ++j)
            acc[j] += lrelu(bb[j] + gv.x*w[j].x + gv.y*w[j].y + gv.z*w[j].z + gv.w*w[j].w);
    }
    const float s = 1.f/16.f;
    short* dst = (cg < 8) ? ((short*)x2 + (size_t)p*128 + c0)
                          : ((short*)x3 + (size_t)p*256 + c0);
    bf16x8 o;
#pragma unroll
    for (int j = 0; j < 8; ++j) o[j] = f2bs(acc[j] * s);
    *(bf16x8*)dst = o;
}

// ---------------------------------------------------------------------------
// x1 = LR(input @ W_init^T + b_init), MFMA, bf16 pre-converted weights.
// Block = 64 rows (4 waves x 16); wave covers all 64 n (4 nt). Grid 625.
// x1 lives in d_out scratch (consumed by gather1 BEFORE ident_mfma
// overwrites d_out).
// ---------------------------------------------------------------------------
__global__ void __launch_bounds__(256) mlp_init_mfma(
    const float* __restrict__ X,     // [BN,256]
    const short* __restrict__ Wnb,   // [64,256] bf16
    const float* __restrict__ bias,  // [64]
    __hip_bfloat16* __restrict__ Y)  // [BN,64] bf16 (d_out scratch)
{
    int wave = threadIdx.x >> 6, lane = threadIdx.x & 63;
    int r = lane & 15, q = lane >> 4;
    int m0 = blockIdx.x * 64 + wave * 16;
    const float* Xs = X + (size_t)(m0 + r) * DIM + q * 8;
    const short* W0 = Wnb + (size_t)r * DIM + q * 8;   // + nt*16*DIM + kk*32
    f32x4 acc[4];
#pragma unroll
    for (int nt = 0; nt < 4; ++nt) acc[nt] = (f32x4){0.f,0.f,0.f,0.f};
#pragma unroll
    for (int kk = 0; kk < 8; ++kk) {
        bf16x8 a = ldf32_bf16x8(Xs + kk * 32);
#pragma unroll
        for (int nt = 0; nt < 4; ++nt) {
            bf16x8 b = *(const bf16x8*)(W0 + (size_t)nt * (16 * DIM) + kk * 32);
            acc[nt] = __builtin_amdgcn_mfma_f32_16x16x32_bf16(a, b, acc[nt], 0, 0, 0);
        }
    }
#pragma unroll
    for (int nt = 0; nt < 4; ++nt) {
        int col = nt * 16 + r;
        float bv = bias[col];
#pragma unroll
        for (int i = 0; i < 4; ++i) {
            float v = lrelu(acc[nt][i] + bv);
            Y[(size_t)(m0 + q*4 + i) * 64 + col] = __float2bfloat16(v);
        }
    }
}

// ---------------------------------------------------------------------------
// gather-mean of x1 rows -> x2[:,64:128]. 8 lanes/point, bf16x8 loads.
// ---------------------------------------------------------------------------
__global__ void __launch_bounds__(256) gather1_kernel(
    const int* __restrict__ idxw, const int* __restrict__ flag,
    const __hip_bfloat16* __restrict__ x1,    // [BN,64]
    __hip_bfloat16* __restrict__ x2)          // [BN,128]
{
    int t = blockIdx.x * 256 + threadIdx.x;
    int p = t >> 3, j = t & 7;
    if (p >= BN) return;
    int dual = (*flag == 0) ? 2 : 1;
    int base = (p >= NPTS) ? NPTS : 0;
    const int* ip = idxw + (size_t)p * KNN * dual;
    float acc[8];
#pragma unroll
    for (int i = 0; i < 8; ++i) acc[i] = 0.f;
#pragma unroll
    for (int k = 0; k < KNN; ++k) {
        int row = base + ip[k * dual];
        bf16x8 v = *(const bf16x8*)((const short*)x1 + (size_t)row * 64 + j * 8);
#pragma unroll
        for (int i = 0; i < 8; ++i) acc[i] += bs2f(v[i]);
    }
    bf16x8 o;
#pragma unroll
    for (int i = 0; i < 8; ++i) o[i] = f2bs(acc[i] * (1.f/16.f));
    *(bf16x8*)((short*)x2 + (size_t)p * 128 + 64 + j * 8) = o;
}

// ---------------------------------------------------------------------------
// gather-mean of x2 rows -> x3[:,128:256]. 16 lanes/point, bf16x8 loads.
// ---------------------------------------------------------------------------
__global__ void __launch_bounds__(256) gather2_kernel(
    const int* __restrict__ idxw, const int* __restrict__ flag,
    const __hip_bfloat16* __restrict__ x2,    // [BN,128]
    __hip_bfloat16* __restrict__ x3)          // [BN,256]
{
    int t = blockIdx.x * 256 + threadIdx.x;
    int p = t >> 4, j = t & 15;
    if (p >= BN) return;
    int dual = (*flag == 0) ? 2 : 1;
    int base = (p >= NPTS) ? NPTS : 0;
    const int* ip = idxw + (size_t)p * KNN * dual;
    float acc[8];
#pragma unroll
    for (int i = 0; i < 8; ++i) acc[i] = 0.f;
#pragma unroll
    for (int k = 0; k < KNN; ++k) {
        int row = base + ip[k * dual];
        bf16x8 v = *(const bf16x8*)((const short*)x2 + (size_t)row * 128 + j * 8);
#pragma unroll
        for (int i = 0; i < 8; ++i) acc[i] += bs2f(v[i]);
    }
    bf16x8 o;
#pragma unroll
    for (int i = 0; i < 8; ++i) o[i] = f2bs(acc[i] * (1.f/16.f));
    *(bf16x8*)((short*)x3 + (size_t)p * 256 + 128 + j * 8) = o;
}

// ---------------------------------------------------------------------------
// Weight-stationary GEMM core. Block = 512 thr (8 waves), grid (256, 2):
// y = n-half. Block DMAs its 64 KB weight half into LDS ONCE (one barrier),
// then each wave processes whole 16-row M-tiles barrier-free:
// a-frags in regs -> 64 ds_read_b128 + 64 MFMA + epilogue. LDS layout
// [kk*4+q][n' 0..127][8] -> ds_read banks spread optimally (8 cyc/inst).
// ---------------------------------------------------------------------------

// ident: OUT = LR(input @ Wi^T + bi)  (writes ALL of d_out; runs after
// gather1 so the x1 scratch in d_out is dead)
__global__ void __launch_bounds__(512) ident_mfma(
    const float* __restrict__ X,              // [BN,256] fp32
    const short* __restrict__ WtI,            // tiled bf16 [kk][q][n][8]
    const float* __restrict__ Bi,             // [256]
    float* __restrict__ OUT)                  // [BN,256] fp32
{
    __shared__ short wbuf[32768];             // 64 KB: one n-half, all kk
    int t = threadIdx.x;
    int wave = t >> 6, lane = t & 63;
    int r = lane & 15, q = lane >> 4;
    int h = blockIdx.y;
    // DMA 64 KB: per wave 4 (kk,q)-pairs, 2 KB each
    {
        const char* W8 = (const char*)WtI;
        char* L8 = (char*)wbuf;
#pragma unroll
        for (int i = 0; i < 4; ++i) {
            int pi = wave * 4 + i;
            const char* src = W8 + (size_t)pi * 4096 + h * 2048 + lane * 16;
            char* dst = L8 + (size_t)pi * 2048 + lane * 16;
            dma16(src, dst);
            dma16(src + 1024, dst + 1024);
        }
    }
    __syncthreads();

    for (int tile = blockIdx.x * 8 + wave; tile < 2500; tile += 2048) {
        int p0 = tile * 16;
        const float* xr = X + (size_t)(p0 + r) * DIM + q * 8;
        bf16x8 a[8];
#pragma unroll
        for (int kk = 0; kk < 8; ++kk) a[kk] = ldf32_bf16x8(xr + kk * 32);
        f32x4 acc[8];
#pragma unroll
        for (int nt = 0; nt < 8; ++nt) acc[nt] = (f32x4){0.f,0.f,0.f,0.f};
#pragma unroll
        for (int kk = 0; kk < 8; ++kk) {
#pragma unroll
            for (int nt = 0; nt < 8; ++nt) {
                bf16x8 b = *(const bf16x8*)&wbuf[((kk*4 + q)*128 + nt*16 + r) * 8];
                acc[nt] = __builtin_amdgcn_mfma_f32_16x16x32_bf16(a[kk], b, acc[nt], 0, 0, 0);
            }
        }
#pragma unroll
        for (int nt = 0; nt < 8; ++nt) {
            int col = h * 128 + nt * 16 + r;
            float bv = Bi[col];
#pragma unroll
            for (int i = 0; i < 4; ++i)
                OUT[(size_t)(p0 + q*4 + i) * DIM + col] = lrelu(acc[nt][i] + bv);
        }
    }
}

// final: OUT += LR(x3 @ Wf^T + bf)  (RMW, same thread reads & writes)
__global__ void __launch_bounds__(512) final_mfma(
    const __hip_bfloat16* __restrict__ X3,    // [BN,256] bf16 ws
    const short* __restrict__ WtF,            // tiled bf16 [kk][q][n][8]
    const float* __restrict__ Bf,             // [256]
    float* __restrict__ OUT)                  // [BN,256] fp32
{
    __shared__ short wbuf[32768];             // 64 KB
    int t = threadIdx.x;
    int wave = t >> 6, lane = t & 63;
    int r = lane & 15, q = lane >> 4;
    int h = blockIdx.y;
    {
        const char* W8 = (const char*)WtF;
        char* L8 = (char*)wbuf;
#pragma unroll
        for (int i = 0; i < 4; ++i) {
            int pi = wave * 4 + i;
            const char* src = W8 + (size_t)pi * 4096 + h * 2048 + lane * 16;
            char* dst = L8 + (size_t)pi * 2048 + lane * 16;
            dma16(src, dst);
            dma16(src + 1024, dst + 1024);
        }
    }
    __syncthreads();

    for (int tile = blockIdx.x * 8 + wave; tile < 2500; tile += 2048) {
        int p0 = tile * 16;
        const short* xr = (const short*)X3 + (size_t)(p0 + r) * DIM + q * 8;
        bf16x8 a[8];
#pragma unroll
        for (int kk = 0; kk < 8; ++kk) a[kk] = *(const bf16x8*)(xr + kk * 32);
        f32x4 acc[8];
#pragma unroll
        for (int nt = 0; nt < 8; ++nt) acc[nt] = (f32x4){0.f,0.f,0.f,0.f};
#pragma unroll
        for (int kk = 0; kk < 8; ++kk) {
#pragma unroll
            for (int nt = 0; nt < 8; ++nt) {
                bf16x8 b = *(const bf16x8*)&wbuf[((kk*4 + q)*128 + nt*16 + r) * 8];
                acc[nt] = __builtin_amdgcn_mfma_f32_16x16x32_bf16(a[kk], b, acc[nt], 0, 0, 0);
            }
        }
#pragma unroll
        for (int nt = 0; nt < 8; ++nt) {
            int col = h * 128 + nt * 16 + r;
            float bv = Bf[col];
#pragma unroll
            for (int i = 0; i < 4; ++i) {
                size_t o = (size_t)(p0 + q*4 + i) * DIM + col;
                OUT[o] = lrelu(acc[nt][i] + bv) + OUT[o];
            }
        }
    }
}

// ---------------------------------------------------------------------------
extern "C" void kernel_launch(void* const* d_in, const int* in_sizes, int n_in,
                              void* d_out, int out_size, void* d_ws, size_t ws_size,
                              hipStream_t stream)
{
    const float* input  = (const float*)d_in[0];   // [2,20000,256]
    const float* geom   = (const float*)d_in[1];   // [2,20000,16,4]
    const int*   idxw   = (const int*)d_in[2];     // int32/int64 (detected)
    const float* W_init = (const float*)d_in[3];   // [64,256]
    const float* b_init = (const float*)d_in[4];
    const float* W_l1   = (const float*)d_in[5];   // [64,4]
    const float* b_l1   = (const float*)d_in[6];
    const float* W_l2   = (const float*)d_in[7];   // [128,4]
    const float* b_l2   = (const float*)d_in[8];
    const float* W_fin  = (const float*)d_in[9];   // [256,256]
    const float* b_fin  = (const float*)d_in[10];
    const float* W_id   = (const float*)d_in[11];  // [256,256]
    const float* b_id   = (const float*)d_in[12];
    float* out = (float*)d_out;                    // [2,20000,256] fp32

    // ws layout (<= 35.84 MB, proven safe R4-R9):
    //   flag @0 (16B)
    //   WtF 128KB @16 ; WtI 128KB @16+131072 ; Wnb 32KB @16+262144
    //   x2  [BN,128] bf16 @16+5.12e6
    //   x3  [BN,256] bf16 @16+15.36e6
    // x1 [BN,64] bf16 lives in d_out scratch; consumed by gather1, then
    // ident_mfma overwrites all of d_out.
    char* ws = (char*)d_ws;
    int* flag = (int*)ws;
    short* WtF = (short*)(ws + 16);
    short* WtI = (short*)(ws + 16 + 131072);
    short* Wnb = (short*)(ws + 16 + 262144);
    __hip_bfloat16* x2 = (__hip_bfloat16*)(ws + 16 + 5120000);
    __hip_bfloat16* x3 = (__hip_bfloat16*)(ws + 16 + 15360000);
    __hip_bfloat16* x1 = (__hip_bfloat16*)d_out;   // scratch, dead after gather1

    geom_kernel<<<3895, 256, 0, stream>>>(geom, W_l1, b_l1, W_l2, b_l2,
                                          idxw, flag, W_fin, W_id, W_init,
                                          WtF, WtI, Wnb, x2, x3);
    mlp_init_mfma<<<625, 256, 0, stream>>>(input, Wnb, b_init, x1);
    gather1_kernel<<<1250, 256, 0, stream>>>(idxw, flag, x1, x2);
    ident_mfma<<<dim3(256, 2), 512, 0, stream>>>(input, WtI, b_id, out);
    gather2_kernel<<<2500, 256, 0, stream>>>(idxw, flag, x2, x3);
    final_mfma<<<dim3(256, 2), 512, 0, stream>>>(x3, WtF, b_fin, out);
}

// Round 11
// 225.496 us; speedup vs baseline: 1.3634x; 1.3634x over previous
//
#include <hip/hip_runtime.h>
#include <hip/hip_bf16.h>

// Problem constants (reference: B=2, N=20000, K=16, DIM=256)
// Established facts (R1-R10):
//   - float tensors fp32; idx int32/int64 runtime-detected; d_out fp32
//   - MFMA 16x16x32_bf16 gemm-BT fragments + C/D map verified
//   - R5-R8: global->VGPR weight loads serialize (load->vmcnt(0)->use); use
//     LDS (DMA) for weights. R9 final (60 us) = best GEMM structure so far.
//   - R10: two-kernel weight-stationary + OUT RMW added ~230 MB HBM -> regressed.
//     Reverted. This round: shfl-based gathers, LDS-weight mlp_init.
//   - LDS quarter-wave phasing: ds_read_b128 with addr = f(r)*16 + q*const
//     is conflict-free (R9 measured 0 conflicts).
#define BN   40000
#define NPTS 20000
#define KNN  16
#define DIM  256

typedef __attribute__((ext_vector_type(8))) short bf16x8;   // 8 bf16 = 4 VGPRs
typedef __attribute__((ext_vector_type(4))) float f32x4;

__device__ __forceinline__ float lrelu(float v) { return v > 0.f ? v : 0.1f * v; }
__device__ __forceinline__ float bs2f(short s) {
    union { unsigned u; float f; } c; c.u = ((unsigned)(unsigned short)s) << 16;
    return c.f;
}
__device__ __forceinline__ short f2bs(float f) {
    __hip_bfloat16 h = __float2bfloat16(f);           // RNE
    return *reinterpret_cast<short*>(&h);
}
__device__ __forceinline__ bf16x8 ldf32_bf16x8(const float* p) {
    const float4 a = ((const float4*)p)[0];
    const float4 b = ((const float4*)p)[1];
    bf16x8 r;
    r[0]=f2bs(a.x); r[1]=f2bs(a.y); r[2]=f2bs(a.z); r[3]=f2bs(a.w);
    r[4]=f2bs(b.x); r[5]=f2bs(b.y); r[6]=f2bs(b.z); r[7]=f2bs(b.w);
    return r;
}

// async global->LDS, 16 B per lane; lds dst = wave-uniform base + lane*16.
__device__ __forceinline__ void dma16(const void* g, void* l) {
    __builtin_amdgcn_global_load_lds(
        (const __attribute__((address_space(1))) unsigned int*)g,
        (__attribute__((address_space(3))) unsigned int*)l, 16, 0, 0);
}

// ---------------------------------------------------------------------------
// geom MLPs (blocks 0..3749) + idx-dtype detect (block 3750) + weight
// conversion (blocks 3751..3894).
// conv: Wf,Wi -> kk-tiled bf16 Wt[kk][mat][q][n][8] (32 KB per kk slice);
//       W_init -> kk-tiled Wnt[kk][q][n<64][8] (32 KB total, LDS-phasing-safe).
// ---------------------------------------------------------------------------
__global__ void __launch_bounds__(256) geom_kernel(
    const float* __restrict__ geom,      // [BN,16,4]
    const float* __restrict__ W1, const float* __restrict__ B1,   // [64,4],[64]
    const float* __restrict__ W2, const float* __restrict__ B2,   // [128,4],[128]
    const int* __restrict__ idxw, int* __restrict__ flag,
    const float* __restrict__ Wf, const float* __restrict__ Wi,   // [256,256]
    const float* __restrict__ Wn,                                  // [64,256]
    short* __restrict__ Wt, short* __restrict__ Wnt,
    __hip_bfloat16* __restrict__ x2,     // [BN,128]
    __hip_bfloat16* __restrict__ x3)     // [BN,256]
{
    if (blockIdx.x >= 3751) {            // ---- weight-convert blocks ----
        int t = (blockIdx.x - 3751) * 256 + threadIdx.x;   // < 36864 exactly
        if (t < 32768) {                 // Wf (t<16384) / Wi -> tiled Wt
            int mat = (t >> 14) & 1;
            int tt  = t & 16383;
            float4 v = mat ? ((const float4*)Wi)[tt] : ((const float4*)Wf)[tt];
            int n  = tt >> 6;
            int k  = (tt & 63) * 4;
            int kk = k >> 5, q = (k >> 3) & 3, j = k & 7;
            short4 o; o.x=f2bs(v.x); o.y=f2bs(v.y); o.z=f2bs(v.z); o.w=f2bs(v.w);
            *(short4*)(Wt + ((size_t)((kk*2 + mat)*4 + q))*2048 + n*8 + j) = o;
        } else {                          // W_init -> tiled Wnt (n<64)
            int tt = t - 32768;           // < 4096
            float4 v = ((const float4*)Wn)[tt];
            int n  = tt >> 6;
            int k  = (tt & 63) * 4;
            int kk = k >> 5, q = (k >> 3) & 3, j = k & 7;
            short4 o; o.x=f2bs(v.x); o.y=f2bs(v.y); o.z=f2bs(v.z); o.w=f2bs(v.w);
            *(short4*)(Wnt + ((size_t)((kk*4 + q)*64 + n))*8 + j) = o;
        }
        return;
    }
    if (blockIdx.x == 3750) {            // ---- detect block (no atomics) ----
        __shared__ int red[256];
        int t = threadIdx.x;
        int v = 0;
#pragma unroll
        for (int it = 0; it < 64; ++it)
            v |= idxw[2 * (t + it * 256) + 1];       // odd words, first 128 KB
        red[t] = v;
        __syncthreads();
        for (int s = 128; s > 0; s >>= 1) {
            if (t < s) red[t] |= red[t + s];
            __syncthreads();
        }
        if (t == 0) *flag = (red[0] != 0) ? 1 : 0;
        return;
    }
    // ---- geom blocks: 3750 x 256 = 960000 threads = 40000 pts x 24 ----
    int tid = blockIdx.x * 256 + threadIdx.x;
    int p  = tid / 24;
    int cg = tid - p * 24;               // 0..23 -> 8 channels each
    const float4* g = (const float4*)(geom + (size_t)p * (KNN * 4));
    const float4* Wp; const float* Bp; int c0;
    if (cg < 8) { c0 = cg * 8;       Wp = (const float4*)W1; Bp = B1; }
    else        { c0 = (cg - 8) * 8; Wp = (const float4*)W2; Bp = B2; }
    float4 w[8]; float bb[8];
#pragma unroll
    for (int j = 0; j < 8; ++j) { w[j] = Wp[c0 + j]; bb[j] = Bp[c0 + j]; }
    float acc[8];
#pragma unroll
    for (int j = 0; j < 8; ++j) acc[j] = 0.f;
#pragma unroll
    for (int k = 0; k < KNN; ++k) {
        float4 gv = g[k];
#pragma unroll
        for (int j = 0; j < 8; ++j)
            acc[j] += lrelu(bb[j] + gv.x*w[j].x + gv.y*w[j].y + gv.z*w[j].z + gv.w*w[j].w);
    }
    const float s = 1.f/16.f;
    short* dst = (cg < 8) ? ((short*)x2 + (size_t)p*128 + c0)
                          : ((short*)x3 + (size_t)p*256 + c0);
    bf16x8 o;
#pragma unroll
    for (int j = 0; j < 8; ++j) o[j] = f2bs(acc[j] * s);
    *(bf16x8*)dst = o;
}

// ---------------------------------------------------------------------------
// x1 = LR(input @ W_init^T + b_init), MFMA. Weights (32 KB tiled) DMA'd to
// LDS once, ONE barrier; A-frags hoisted as a 16-load burst before barrier;
// inner loop = pure ds_read + MFMA. Block = 64 rows (4 waves x 16). Grid 625.
// ds_read addr = f(r)*16 + q*1KB -> quarter-wave phases conflict-free.
// x1 lives in d_out scratch (consumed by gather1 before final overwrites).
// ---------------------------------------------------------------------------
__global__ void __launch_bounds__(256) mlp_init_mfma(
    const float* __restrict__ X,     // [BN,256]
    const short* __restrict__ Wnt,   // [kk][q][64][8] bf16, 32 KB
    const float* __restrict__ bias,  // [64]
    __hip_bfloat16* __restrict__ Y)  // [BN,64] bf16 (d_out scratch)
{
    __shared__ short wbuf[16384];    // 32 KB
    int t = threadIdx.x;
    int wave = t >> 6, lane = t & 63;
    int r = lane & 15, q = lane >> 4;
    // DMA the full 32 KB (4 waves x 8 x 1 KB, linear copy)
    {
        const char* W8 = (const char*)Wnt;
        char* L8 = (char*)wbuf;
#pragma unroll
        for (int rd = 0; rd < 8; ++rd) {
            int off = (wave * 8 + rd) * 1024 + lane * 16;
            dma16(W8 + off, L8 + off);
        }
    }
    int m0 = blockIdx.x * 64 + wave * 16;
    const float* Xs = X + (size_t)(m0 + r) * DIM + q * 8;
    bf16x8 a[8];
#pragma unroll
    for (int kk = 0; kk < 8; ++kk) a[kk] = ldf32_bf16x8(Xs + kk * 32);
    __syncthreads();

    f32x4 acc[4];
#pragma unroll
    for (int nt = 0; nt < 4; ++nt) acc[nt] = (f32x4){0.f,0.f,0.f,0.f};
#pragma unroll
    for (int kk = 0; kk < 8; ++kk) {
#pragma unroll
        for (int nt = 0; nt < 4; ++nt) {
            bf16x8 b = *(const bf16x8*)&wbuf[((kk*4 + q)*64 + nt*16 + r) * 8];
            acc[nt] = __builtin_amdgcn_mfma_f32_16x16x32_bf16(a[kk], b, acc[nt], 0, 0, 0);
        }
    }
#pragma unroll
    for (int nt = 0; nt < 4; ++nt) {
        int col = nt * 16 + r;
        float bv = bias[col];
#pragma unroll
        for (int i = 0; i < 4; ++i) {
            float v = lrelu(acc[nt][i] + bv);
            Y[(size_t)(m0 + q*4 + i) * 64 + col] = __float2bfloat16(v);
        }
    }
}

// ---------------------------------------------------------------------------
// gather-mean of x1 rows -> x2[:,64:128]. 8 lanes/point; each lane loads 2
// indices, neighbors broadcast via __shfl (no redundant idx loads).
// ---------------------------------------------------------------------------
__global__ void __launch_bounds__(256) gather1_kernel(
    const int* __restrict__ idxw, const int* __restrict__ flag,
    const __hip_bfloat16* __restrict__ x1,    // [BN,64]
    __hip_bfloat16* __restrict__ x2)          // [BN,128]
{
    int t = blockIdx.x * 256 + threadIdx.x;   // 320000 exactly = BN*8
    int p = t >> 3, j = t & 7;
    int lane = threadIdx.x & 63;
    int dual = (*flag == 0) ? 2 : 1;
    int base = (p >= NPTS) ? NPTS : 0;
    int i0 = idxw[((size_t)p * 16 + 2*j)     * dual];   // neighbor 2j
    int i1 = idxw[((size_t)p * 16 + 2*j + 1) * dual];   // neighbor 2j+1
    int g8 = lane & 56;
    float acc[8];
#pragma unroll
    for (int i = 0; i < 8; ++i) acc[i] = 0.f;
#pragma unroll
    for (int k = 0; k < 8; ++k) {
        int rA = base + __shfl(i0, g8 + k, 64);         // neighbor 2k
        int rB = base + __shfl(i1, g8 + k, 64);         // neighbor 2k+1
        bf16x8 vA = *(const bf16x8*)((const short*)x1 + (size_t)rA * 64 + j * 8);
        bf16x8 vB = *(const bf16x8*)((const short*)x1 + (size_t)rB * 64 + j * 8);
#pragma unroll
        for (int i = 0; i < 8; ++i) acc[i] += bs2f(vA[i]) + bs2f(vB[i]);
    }
    bf16x8 o;
#pragma unroll
    for (int i = 0; i < 8; ++i) o[i] = f2bs(acc[i] * (1.f/16.f));
    *(bf16x8*)((short*)x2 + (size_t)p * 128 + 64 + j * 8) = o;
}

// ---------------------------------------------------------------------------
// gather-mean of x2 rows -> x3[:,128:256]. 16 lanes/point; each lane loads 1
// index, neighbors broadcast via __shfl.
// ---------------------------------------------------------------------------
__global__ void __launch_bounds__(256) gather2_kernel(
    const int* __restrict__ idxw, const int* __restrict__ flag,
    const __hip_bfloat16* __restrict__ x2,    // [BN,128]
    __hip_bfloat16* __restrict__ x3)          // [BN,256]
{
    int t = blockIdx.x * 256 + threadIdx.x;   // 640000 exactly = BN*16
    int p = t >> 4, j = t & 15;
    int lane = threadIdx.x & 63;
    int dual = (*flag == 0) ? 2 : 1;
    int base = (p >= NPTS) ? NPTS : 0;
    int myi = idxw[((size_t)p * 16 + j) * dual];
    int g16 = lane & 48;
    float acc[8];
#pragma unroll
    for (int i = 0; i < 8; ++i) acc[i] = 0.f;
#pragma unroll
    for (int k = 0; k < KNN; ++k) {
        int row = base + __shfl(myi, g16 + k, 64);
        bf16x8 v = *(const bf16x8*)((const short*)x2 + (size_t)row * 128 + j * 8);
#pragma unroll
        for (int i = 0; i < 8; ++i) acc[i] += bs2f(v[i]);
    }
    bf16x8 o;
#pragma unroll
    for (int i = 0; i < 8; ++i) o[i] = f2bs(acc[i] * (1.f/16.f));
    *(bf16x8*)((short*)x3 + (size_t)p * 256 + 128 + j * 8) = o;
}

// ---------------------------------------------------------------------------
// out = LR(x3 @ Wf^T + bf) + LR(input @ Wi^T + bi), fp32 out. MFMA.
// R9-proven structure (60 us): block = 16 rows x full N=256, A-frags in regs,
// per-kk 32 KB weight slice DMA'd to LDS, 2-barrier K-loop. Grid 2500.
// ---------------------------------------------------------------------------
__global__ void __launch_bounds__(256) final_mfma(
    const __hip_bfloat16* __restrict__ X3,    // [BN,256] bf16 ws
    const float* __restrict__ RES,            // [BN,256] fp32
    const short* __restrict__ Wt,             // tiled bf16 [kk][mat][q][n][8]
    const float* __restrict__ Bf,             // [256]
    const float* __restrict__ Bi,             // [256]
    float* __restrict__ OUT)                  // [BN,256] fp32
{
    __shared__ short wbuf[16384];             // 32 KB: one kk slice, both mats
    int t = threadIdx.x;
    int wave = t >> 6, lane = t & 63;
    int r = lane & 15, q = lane >> 4;
    int p0 = blockIdx.x * 16;

    const char* WtB = (const char*)Wt;
    char* wbufB = (char*)wbuf;
    {
        const char* src0 = WtB + wave * 1024 + lane * 16;
#pragma unroll
        for (int rd = 0; rd < 8; ++rd)
            dma16(src0 + rd * 4096, wbufB + rd * 4096 + wave * 1024);
    }

    bf16x8 a1f[8], a2f[8];
    {
        const short* x3r = (const short*)X3 + (size_t)(p0 + r) * DIM + q * 8;
        const float* rsr = RES + (size_t)(p0 + r) * DIM + q * 8;
#pragma unroll
        for (int kk = 0; kk < 8; ++kk) {
            a1f[kk] = *(const bf16x8*)(x3r + kk * 32);
            a2f[kk] = ldf32_bf16x8(rsr + kk * 32);
        }
    }

    f32x4 acc1[4], acc2[4];
#pragma unroll
    for (int nt = 0; nt < 4; ++nt) {
        acc1[nt] = (f32x4){0.f,0.f,0.f,0.f};
        acc2[nt] = (f32x4){0.f,0.f,0.f,0.f};
    }

#pragma unroll
    for (int kk = 0; kk < 8; ++kk) {
        __syncthreads();                  // drain DMA(kk) -> wbuf ready
#pragma unroll
        for (int nt = 0; nt < 4; ++nt) {
            int n = wave * 64 + nt * 16 + r;
            bf16x8 b1 = *(const bf16x8*)&wbuf[(size_t)q * 2048 + n * 8];
            bf16x8 b2 = *(const bf16x8*)&wbuf[(size_t)(4 + q) * 2048 + n * 8];
            acc1[nt] = __builtin_amdgcn_mfma_f32_16x16x32_bf16(a1f[kk], b1, acc1[nt], 0, 0, 0);
            acc2[nt] = __builtin_amdgcn_mfma_f32_16x16x32_bf16(a2f[kk], b2, acc2[nt], 0, 0, 0);
        }
        if (kk < 7) {
            __syncthreads();              // all waves done reading wbuf
            const char* src = WtB + (size_t)(kk + 1) * 32768 + wave * 1024 + lane * 16;
#pragma unroll
            for (int rd = 0; rd < 8; ++rd)
                dma16(src + rd * 4096, wbufB + rd * 4096 + wave * 1024);
        }
    }

#pragma unroll
    for (int nt = 0; nt < 4; ++nt) {
        int col = wave * 64 + nt * 16 + r;
        float bfv = Bf[col], biv = Bi[col];
#pragma unroll
        for (int i = 0; i < 4; ++i) {
            float v = lrelu(acc1[nt][i] + bfv) + lrelu(acc2[nt][i] + biv);
            OUT[(size_t)(p0 + q*4 + i) * DIM + col] = v;
        }
    }
}

// ---------------------------------------------------------------------------
extern "C" void kernel_launch(void* const* d_in, const int* in_sizes, int n_in,
                              void* d_out, int out_size, void* d_ws, size_t ws_size,
                              hipStream_t stream)
{
    const float* input  = (const float*)d_in[0];   // [2,20000,256]
    const float* geom   = (const float*)d_in[1];   // [2,20000,16,4]
    const int*   idxw   = (const int*)d_in[2];     // int32/int64 (detected)
    const float* W_init = (const float*)d_in[3];   // [64,256]
    const float* b_init = (const float*)d_in[4];
    const float* W_l1   = (const float*)d_in[5];   // [64,4]
    const float* b_l1   = (const float*)d_in[6];
    const float* W_l2   = (const float*)d_in[7];   // [128,4]
    const float* b_l2   = (const float*)d_in[8];
    const float* W_fin  = (const float*)d_in[9];   // [256,256]
    const float* b_fin  = (const float*)d_in[10];
    const float* W_id   = (const float*)d_in[11];  // [256,256]
    const float* b_id   = (const float*)d_in[12];
    float* out = (float*)d_out;                    // [2,20000,256] fp32

    // ws layout (<= 35.84 MB, proven safe R4-R10):
    //   flag @0 (16B)
    //   Wt  tiled bf16 256KB @16 ; Wnt tiled bf16 32KB @16+262144
    //   x2  [BN,128] bf16 @16+5.12e6
    //   x3  [BN,256] bf16 @16+15.36e6
    // x1 [BN,64] bf16 lives in d_out scratch; consumed by gather1, then
    // final_mfma overwrites all of d_out.
    char* ws = (char*)d_ws;
    int* flag = (int*)ws;
    short* Wt  = (short*)(ws + 16);
    short* Wnt = (short*)(ws + 16 + 262144);
    __hip_bfloat16* x2 = (__hip_bfloat16*)(ws + 16 + 5120000);
    __hip_bfloat16* x3 = (__hip_bfloat16*)(ws + 16 + 15360000);
    __hip_bfloat16* x1 = (__hip_bfloat16*)d_out;   // scratch, dead after gather1

    geom_kernel<<<3895, 256, 0, stream>>>(geom, W_l1, b_l1, W_l2, b_l2,
                                          idxw, flag, W_fin, W_id, W_init,
                                          Wt, Wnt, x2, x3);
    mlp_init_mfma<<<625, 256, 0, stream>>>(input, Wnt, b_init, x1);
    gather1_kernel<<<1250, 256, 0, stream>>>(idxw, flag, x1, x2);
    gather2_kernel<<<2500, 256, 0, stream>>>(idxw, flag, x2, x3);
    final_mfma<<<2500, 256, 0, stream>>>(x3, input, Wt, b_fin, b_id, out);
}